// Round 1
// baseline (217.606 us; speedup 1.0000x reference)
//
#include <hip/hip_runtime.h>
#include <stdint.h>

// FP4 quant-dequant, faithful to the JAX reference in float32 arithmetic.
// Pipeline: k_scales (per-block 95th pct of |x|) -> k_reduce (global min/max
// of scales) -> k_dscale (double-quantize scales) -> k_quant (per-element
// nearest-level quantize + dequantize).

#define BLK 64
#define WG 256
#define NWG_SCALES 1024

__global__ __launch_bounds__(WG) void k_scales(const float* __restrict__ x,
                                               int n, int nblocks,
                                               float* __restrict__ scales,
                                               float* __restrict__ partMin,
                                               float* __restrict__ partMax) {
    const int lane = threadIdx.x & 63;
    const int waveInWg = threadIdx.x >> 6;
    const int wavesPerWg = WG >> 6;            // 4
    const int gwave = blockIdx.x * wavesPerWg + waveInWg;
    const int nwaves = gridDim.x * wavesPerWg;

    // JAX f32 quantile weights: q = 0.95f * 63.0f (f32), low=59, high=60
    const float qs = 0.95f * 63.0f;            // 59.849998474121094f
    const float hw = qs - 59.0f;               // high_weight
    const float lw = 60.0f - qs;               // low_weight

    float lmin = 3.402823466e+38f;
    float lmax = 0.0f;

    for (int b = gwave; b < nblocks; b += nwaves) {
        const int idx = b * BLK + lane;
        float xv = (idx < n) ? x[idx] : 0.0f;  // reference zero-pads
        float a = fabsf(xv);
        float m4 = 0.0f, m5 = 0.0f;            // 4th and 5th largest
#pragma unroll
        for (int k = 0; k < 5; ++k) {
            float m = a;
#pragma unroll
            for (int off = 32; off > 0; off >>= 1)
                m = fmaxf(m, __shfl_xor(m, off, 64));
            if (k == 3) m4 = m;                // sorted v[60]
            if (k == 4) m5 = m;                // sorted v[59]
            if (k < 4) {
                unsigned long long tie = __ballot(a == m);
                int src = __ffsll(tie) - 1;    // remove exactly one instance
                if (lane == src) a = -1.0f;
            }
        }
        // result = low_value*low_weight + high_value*high_weight (JAX order),
        // pinned to mul/mul/add (no fma contraction).
        float s = __fadd_rn(__fmul_rn(m5, lw), __fmul_rn(m4, hw));
        s = fmaxf(s, 1e-8f);
        if (lane == 0) scales[b] = s;
        lmin = fminf(lmin, s);
        lmax = fmaxf(lmax, s);
    }

    __shared__ float smn[4], smx[4];
    if (lane == 0) { smn[waveInWg] = lmin; smx[waveInWg] = lmax; }
    __syncthreads();
    if (threadIdx.x == 0) {
        float mn = smn[0], mx = smx[0];
#pragma unroll
        for (int i = 1; i < 4; ++i) { mn = fminf(mn, smn[i]); mx = fmaxf(mx, smx[i]); }
        partMin[blockIdx.x] = mn;
        partMax[blockIdx.x] = mx;
    }
}

__global__ __launch_bounds__(WG) void k_reduce(const float* __restrict__ partMin,
                                               const float* __restrict__ partMax,
                                               int nparts,
                                               float* __restrict__ hdr) {
    float mn = 3.402823466e+38f, mx = 0.0f;
    for (int i = threadIdx.x; i < nparts; i += WG) {
        mn = fminf(mn, partMin[i]);
        mx = fmaxf(mx, partMax[i]);
    }
#pragma unroll
    for (int off = 32; off > 0; off >>= 1) {
        mn = fminf(mn, __shfl_xor(mn, off, 64));
        mx = fmaxf(mx, __shfl_xor(mx, off, 64));
    }
    __shared__ float smn[4], smx[4];
    int lane = threadIdx.x & 63, w = threadIdx.x >> 6;
    if (lane == 0) { smn[w] = mn; smx[w] = mx; }
    __syncthreads();
    if (threadIdx.x == 0) {
        float fmn = smn[0], fmx = smx[0];
#pragma unroll
        for (int i = 1; i < 4; ++i) { fmn = fminf(fmn, smn[i]); fmx = fmaxf(fmx, smx[i]); }
        hdr[0] = fmn; hdr[1] = fmx;
    }
}

__global__ __launch_bounds__(WG) void k_dscale(const float* __restrict__ scales,
                                               const float* __restrict__ hdr,
                                               int nblocks,
                                               float* __restrict__ dscales) {
    int i = blockIdx.x * WG + threadIdx.x;
    if (i >= nblocks) return;
    float smin = hdr[0], smax = hdr[1];
    float s = scales[i];
    float ds;
    if (smax > smin) {
        float ss = __fdiv_rn(__fsub_rn(smax, smin), 255.0f);
        float q = rintf(__fdiv_rn(__fsub_rn(s, smin), ss));   // round half-even
        q = fminf(fmaxf(q, 0.0f), 255.0f);                    // clip AFTER round
        ds = __fmul_rn(q, ss);
    } else {
        ds = 0.0f;  // q=0, scale_scale=1 -> deq 0
    }
    dscales[i] = ds;
}

__global__ __launch_bounds__(WG) void k_quant(const float* __restrict__ x,
                                              const float* __restrict__ scales,
                                              const float* __restrict__ dscales,
                                              int n,
                                              float* __restrict__ out) {
    const float T[11] = {-3.0f, -2.0f, -1.5f, -1.0f, -0.75f, 0.0f,
                         0.75f, 1.0f, 1.5f, 2.0f, 3.0f};
    int t = blockIdx.x * WG + threadIdx.x;
    int i = t * 4;
    if (i >= n) return;
    int b = i >> 6;                 // 4-aligned group never crosses a 64-block
    float s = scales[b];
    float ds = dscales[b];

    if (i + 3 < n) {
        const float4 xv = *reinterpret_cast<const float4*>(x + i);
        float xs[4] = {xv.x, xv.y, xv.z, xv.w};
        float os[4];
#pragma unroll
        for (int j = 0; j < 4; ++j) {
            float xn = __fdiv_rn(xs[j], s);
            float bd = fabsf(xn - T[0]);
            float bv = T[0];
#pragma unroll
            for (int k = 1; k < 11; ++k) {
                float d = fabsf(xn - T[k]);
                if (d < bd) { bd = d; bv = T[k]; }   // strict < = first-index ties
            }
            os[j] = __fmul_rn(bv, ds);
        }
        *reinterpret_cast<float4*>(out + i) =
            make_float4(os[0], os[1], os[2], os[3]);
    } else {
        for (int j = 0; j < 4 && i + j < n; ++j) {
            float xn = __fdiv_rn(x[i + j], s);
            float bd = fabsf(xn - T[0]);
            float bv = T[0];
#pragma unroll
            for (int k = 1; k < 11; ++k) {
                float d = fabsf(xn - T[k]);
                if (d < bd) { bd = d; bv = T[k]; }
            }
            out[i + j] = __fmul_rn(bv, ds);
        }
    }
}

extern "C" void kernel_launch(void* const* d_in, const int* in_sizes, int n_in,
                              void* d_out, int out_size, void* d_ws, size_t ws_size,
                              hipStream_t stream) {
    const float* x = (const float*)d_in[0];
    float* out = (float*)d_out;
    const int n = in_sizes[0];
    const int nblocks = (n + BLK - 1) / BLK;

    float* ws = (float*)d_ws;
    float* scales  = ws;                      // nblocks floats
    float* dscales = ws + nblocks;            // nblocks floats
    float* partMin = ws + 2 * nblocks;        // NWG_SCALES floats
    float* partMax = partMin + NWG_SCALES;    // NWG_SCALES floats
    float* hdr     = partMax + NWG_SCALES;    // 2 floats (smin, smax)

    k_scales<<<NWG_SCALES, WG, 0, stream>>>(x, n, nblocks, scales, partMin, partMax);
    k_reduce<<<1, WG, 0, stream>>>(partMin, partMax, NWG_SCALES, hdr);
    k_dscale<<<(nblocks + WG - 1) / WG, WG, 0, stream>>>(scales, hdr, nblocks, dscales);
    k_quant<<<((n + 3) / 4 + WG - 1) / WG, WG, 0, stream>>>(x, scales, dscales, n, out);
}

// Round 2
// 126.040 us; speedup vs baseline: 1.7265x; 1.7265x over previous
//
#include <hip/hip_runtime.h>
#include <stdint.h>

// FP4 quant-dequant, faithful to the JAX reference in float32 arithmetic.
// v2: k_scales is thread-serial (1 thread = 1 block of 64), no cross-lane
// chain; k_dscale folded into k_quant; argmin replaced by boundary ladder.

#define BLK 64
#define WG 256
#define FLT_BIG 3.402823466e+38f

// Branchless insert of `a` into descending-sorted top-5 register array.
__device__ __forceinline__ void ins5(float (&t)[5], float a) {
#pragma unroll
    for (int k = 0; k < 4; ++k) {
        float m = fmaxf(t[k], a);
        a = fminf(t[k], a);
        t[k] = m;
    }
    t[4] = fmaxf(t[4], a);
}

__global__ __launch_bounds__(WG) void k_scales(const float* __restrict__ x,
                                               int n, int nblocks,
                                               float* __restrict__ scales,
                                               float* __restrict__ partMin,
                                               float* __restrict__ partMax) {
    const int b = blockIdx.x * WG + threadIdx.x;
    const bool valid = (b < nblocks);

    float s = 0.0f;
    if (valid) {
        float4 v[16];
        const int base = b * BLK;
        if (base + BLK <= n) {
            const float4* x4 = reinterpret_cast<const float4*>(x + base);
#pragma unroll
            for (int j = 0; j < 16; ++j) v[j] = x4[j];
        } else {
            for (int j = 0; j < 16; ++j) {
                float tmp[4];
                for (int k = 0; k < 4; ++k) {
                    int idx = base + j * 4 + k;
                    tmp[k] = (idx < n) ? x[idx] : 0.0f;  // reference zero-pads
                }
                v[j] = make_float4(tmp[0], tmp[1], tmp[2], tmp[3]);
            }
        }
        // Two independent insertion chains for ILP; abs>=0 so 0-init is safe.
        float A[5] = {0.f, 0.f, 0.f, 0.f, 0.f};
        float B[5] = {0.f, 0.f, 0.f, 0.f, 0.f};
#pragma unroll
        for (int j = 0; j < 16; j += 2) {
            ins5(A, fabsf(v[j].x));     ins5(B, fabsf(v[j + 1].x));
            ins5(A, fabsf(v[j].y));     ins5(B, fabsf(v[j + 1].y));
            ins5(A, fabsf(v[j].z));     ins5(B, fabsf(v[j + 1].z));
            ins5(A, fabsf(v[j].w));     ins5(B, fabsf(v[j + 1].w));
        }
#pragma unroll
        for (int k = 0; k < 5; ++k) ins5(A, B[k]);

        // JAX f32 quantile: q = 0.95f*63.0f; result = v59*lw + v60*hw
        const float qs = 0.95f * 63.0f;      // 59.849998474121094f
        const float hw = qs - 59.0f;
        const float lw = 60.0f - qs;
        // A[3] = 4th largest = sorted v[60]; A[4] = 5th largest = v[59]
        s = __fadd_rn(__fmul_rn(A[4], lw), __fmul_rn(A[3], hw));
        s = fmaxf(s, 1e-8f);
        scales[b] = s;
    }

    // Workgroup min/max partials (no global atomics).
    float mn = valid ? s : FLT_BIG;
    float mx = valid ? s : 0.0f;
#pragma unroll
    for (int off = 32; off > 0; off >>= 1) {
        mn = fminf(mn, __shfl_xor(mn, off, 64));
        mx = fmaxf(mx, __shfl_xor(mx, off, 64));
    }
    __shared__ float smn[4], smx[4];
    const int lane = threadIdx.x & 63, w = threadIdx.x >> 6;
    if (lane == 0) { smn[w] = mn; smx[w] = mx; }
    __syncthreads();
    if (threadIdx.x == 0) {
        float fmn = smn[0], fmx = smx[0];
#pragma unroll
        for (int i = 1; i < 4; ++i) { fmn = fminf(fmn, smn[i]); fmx = fmaxf(fmx, smx[i]); }
        partMin[blockIdx.x] = fmn;
        partMax[blockIdx.x] = fmx;
    }
}

__global__ __launch_bounds__(WG) void k_reduce(const float* __restrict__ partMin,
                                               const float* __restrict__ partMax,
                                               int nparts,
                                               float* __restrict__ hdr) {
    float mn = FLT_BIG, mx = 0.0f;
    for (int i = threadIdx.x; i < nparts; i += WG) {
        mn = fminf(mn, partMin[i]);
        mx = fmaxf(mx, partMax[i]);
    }
#pragma unroll
    for (int off = 32; off > 0; off >>= 1) {
        mn = fminf(mn, __shfl_xor(mn, off, 64));
        mx = fmaxf(mx, __shfl_xor(mx, off, 64));
    }
    __shared__ float smn[4], smx[4];
    int lane = threadIdx.x & 63, w = threadIdx.x >> 6;
    if (lane == 0) { smn[w] = mn; smx[w] = mx; }
    __syncthreads();
    if (threadIdx.x == 0) {
        float fmn = smn[0], fmx = smx[0];
#pragma unroll
        for (int i = 1; i < 4; ++i) { fmn = fminf(fmn, smn[i]); fmx = fmaxf(fmx, smx[i]); }
        hdr[0] = fmn; hdr[1] = fmx;
    }
}

// Nearest FP4 level via boundary ladder. Equivalent to first-index argmin:
// midpoints and all partial sums are exact dyadics; ties at exact midpoints
// go to the lower-index (more negative) level in both formulations.
__device__ __forceinline__ float qlevel(float xn) {
    float bv = -3.0f;
    bv += (xn > -2.5f)   ? 1.0f  : 0.0f;
    bv += (xn > -1.75f)  ? 0.5f  : 0.0f;
    bv += (xn > -1.25f)  ? 0.5f  : 0.0f;
    bv += (xn > -0.875f) ? 0.25f : 0.0f;
    bv += (xn > -0.375f) ? 0.75f : 0.0f;
    bv += (xn > 0.375f)  ? 0.75f : 0.0f;
    bv += (xn > 0.875f)  ? 0.25f : 0.0f;
    bv += (xn > 1.25f)   ? 0.5f  : 0.0f;
    bv += (xn > 1.75f)   ? 0.5f  : 0.0f;
    bv += (xn > 2.5f)    ? 1.0f  : 0.0f;
    return bv;
}

__global__ __launch_bounds__(WG) void k_quant(const float* __restrict__ x,
                                              const float* __restrict__ scales,
                                              const float* __restrict__ hdr,
                                              int n,
                                              float* __restrict__ out) {
    const int t = blockIdx.x * WG + threadIdx.x;
    const int i = t * 4;
    if (i >= n) return;

    const float smin = hdr[0], smax = hdr[1];
    const int b = i >> 6;               // 4-aligned group never crosses a block
    const float s = scales[b];

    // Inline double-quantization of the scale (was k_dscale).
    float ds;
    if (smax > smin) {
        const float ss = __fdiv_rn(__fsub_rn(smax, smin), 255.0f);
        float q = rintf(__fdiv_rn(__fsub_rn(s, smin), ss));   // round half-even
        q = fminf(fmaxf(q, 0.0f), 255.0f);                    // clip AFTER round
        ds = __fmul_rn(q, ss);
    } else {
        ds = 0.0f;   // q=0, scale_scale=1 -> deq 0
    }

    if (i + 3 < n) {
        const float4 xv = *reinterpret_cast<const float4*>(x + i);
        float4 ov;
        ov.x = __fmul_rn(qlevel(__fdiv_rn(xv.x, s)), ds);
        ov.y = __fmul_rn(qlevel(__fdiv_rn(xv.y, s)), ds);
        ov.z = __fmul_rn(qlevel(__fdiv_rn(xv.z, s)), ds);
        ov.w = __fmul_rn(qlevel(__fdiv_rn(xv.w, s)), ds);
        *reinterpret_cast<float4*>(out + i) = ov;
    } else {
        for (int j = 0; j < 4 && i + j < n; ++j)
            out[i + j] = __fmul_rn(qlevel(__fdiv_rn(x[i + j], s)), ds);
    }
}

extern "C" void kernel_launch(void* const* d_in, const int* in_sizes, int n_in,
                              void* d_out, int out_size, void* d_ws, size_t ws_size,
                              hipStream_t stream) {
    const float* x = (const float*)d_in[0];
    float* out = (float*)d_out;
    const int n = in_sizes[0];
    const int nblocks = (n + BLK - 1) / BLK;
    const int nwgScales = (nblocks + WG - 1) / WG;

    float* ws = (float*)d_ws;
    float* scales  = ws;                       // nblocks floats
    float* partMin = ws + nblocks;             // nwgScales floats
    float* partMax = partMin + nwgScales;      // nwgScales floats
    float* hdr     = partMax + nwgScales;      // 2 floats (smin, smax)

    k_scales<<<nwgScales, WG, 0, stream>>>(x, n, nblocks, scales, partMin, partMax);
    k_reduce<<<1, WG, 0, stream>>>(partMin, partMax, nwgScales, hdr);
    k_quant<<<((n + 3) / 4 + WG - 1) / WG, WG, 0, stream>>>(x, scales, hdr, n, out);
}